// Round 1
// baseline (1331.706 us; speedup 1.0000x reference)
//
#include <hip/hip_runtime.h>
#include <math.h>

#define N_    100000
#define E_    1600000
#define ETOT_ 1700000   // E + N self-loops
#define G_    64
#define H_    128
#define L_    3
#define GD_   32
#define NEG_  0.2f
#define EPS_  1e-5f

#define SCAN_B 2048
#define NSCAN  49       // ceil(N_/SCAN_B)

// ---------------- CSR build ----------------

__global__ void k_init(int* cursor, float* pooled, int* gstart, const int* __restrict__ batch) {
    int i = blockIdx.x * 256 + threadIdx.x;
    if (i < N_) cursor[i] = 1;                 // deg starts at 1 (self-loop)
    if (i < L_ * G_ * H_) pooled[i] = 0.f;
    if (i <= G_) {
        // gstart[g] = lower_bound(batch, g); batch is sorted
        int lo = 0, hi = N_;
        while (lo < hi) { int mid = (lo + hi) >> 1; if (batch[mid] < i) lo = mid + 1; else hi = mid; }
        gstart[i] = lo;
    }
}

__global__ void k_hist(const int* __restrict__ edst, int* cursor) {
    int i = blockIdx.x * 256 + threadIdx.x;
    if (i < E_) atomicAdd(&cursor[edst[i]], 1);
}

__global__ __launch_bounds__(256) void k_scan1(const int* __restrict__ deg, int* out, int* bsum) {
    __shared__ int lds[SCAN_B];
    __shared__ int tsum[256];
    int t = threadIdx.x, b = blockIdx.x;
    int base = b * SCAN_B;
    for (int i = t; i < SCAN_B; i += 256) lds[i] = (base + i < N_) ? deg[base + i] : 0;
    __syncthreads();
    int o = t * 8;
    int v[8]; int run = 0;
#pragma unroll
    for (int i = 0; i < 8; i++) { int x = lds[o + i]; v[i] = run; run += x; }
    tsum[t] = run;
    __syncthreads();
    for (int off = 1; off < 256; off <<= 1) {
        int x = (t >= off) ? tsum[t - off] : 0;
        __syncthreads();
        tsum[t] += x;
        __syncthreads();
    }
    int excl = tsum[t] - run;
#pragma unroll
    for (int i = 0; i < 8; i++) lds[o + i] = v[i] + excl;
    __syncthreads();
    for (int i = t; i < SCAN_B; i += 256) if (base + i < N_) out[base + i] = lds[i];
    if (t == 255) bsum[b] = tsum[255];
}

__global__ void k_scan2(int* bsum) {
    if (threadIdx.x == 0) {
        int run = 0;
        for (int i = 0; i < NSCAN; i++) { int x = bsum[i]; bsum[i] = run; run += x; }
    }
}

__global__ void k_scan3(int* rowptr, int* cursor, const int* __restrict__ bsum) {
    int i = blockIdx.x * 256 + threadIdx.x;
    if (i < N_) {
        int v = rowptr[i] + bsum[i >> 11];
        rowptr[i] = v;
        cursor[i] = v;
    }
    if (i == 0) rowptr[N_] = ETOT_;
}

__global__ void k_scatter(const int* __restrict__ esrc, const int* __restrict__ edst,
                          int* cursor, int* __restrict__ colarr) {
    int i = blockIdx.x * 256 + threadIdx.x;
    if (i >= E_ + N_) return;
    int s, d;
    if (i < E_) { s = esrc[i]; d = edst[i]; } else { s = d = i - E_; }
    int pos = atomicAdd(&cursor[d], 1);
    colarr[pos] = s;
}

// ---------------- GEMM: y[N,128] = x[N,128] @ W[128,128] ----------------

__global__ __launch_bounds__(256) void k_gemm(const float* __restrict__ x,
                                              const float* __restrict__ Wl,
                                              float* __restrict__ y) {
    __shared__ float sW[H_ * H_];   // 64 KB
    __shared__ float sx[32 * H_];   // 16 KB
    int tid = threadIdx.x;
    const float4* W4 = (const float4*)Wl;
    float4* sW4 = (float4*)sW;
    for (int i = tid; i < H_ * H_ / 4; i += 256) sW4[i] = W4[i];
    int base = blockIdx.x * 32;
    const float4* x4 = (const float4*)(x + (size_t)base * H_);
    float4* sx4 = (float4*)sx;
    for (int i = tid; i < 32 * H_ / 4; i += 256) sx4[i] = x4[i];
    __syncthreads();
    int c0 = (tid & 15) * 4;
    int r0 = tid >> 4;   // 0..15
#pragma unroll
    for (int pass = 0; pass < 2; pass++) {
        int r = r0 + pass * 16;
        float a0 = 0, a1 = 0, a2 = 0, a3 = 0, b0 = 0, b1 = 0, b2 = 0, b3 = 0;
        const float* xr = &sx[r * H_];
#pragma unroll 8
        for (int k = 0; k < H_; k++) {
            float xv = xr[k];
            const float* wr = &sW[k * H_];
            float4 wa = *(const float4*)(wr + c0);
            float4 wb = *(const float4*)(wr + c0 + 64);
            a0 += xv * wa.x; a1 += xv * wa.y; a2 += xv * wa.z; a3 += xv * wa.w;
            b0 += xv * wb.x; b1 += xv * wb.y; b2 += xv * wb.z; b3 += xv * wb.w;
        }
        float* yr = y + (size_t)(base + r) * H_;
        float4 va = { a0, a1, a2, a3 }, vb = { b0, b1, b2, b3 };
        *(float4*)(yr + c0) = va;
        *(float4*)(yr + c0 + 64) = vb;
    }
}

// ---------------- GATv2 conv: per-dst online softmax + aggregate ----------------
// 32 lanes per dst row (4 dims/lane), 2 rows per wave, 8 rows per block.

__global__ __launch_bounds__(256) void k_conv(const float* __restrict__ xl, const float* __restrict__ xr,
                                              const int* __restrict__ rowptr, const int* __restrict__ colarr,
                                              const float* __restrict__ attl, const float* __restrict__ bcl,
                                              float* __restrict__ h) {
    int tid = threadIdx.x;
    int lane = tid & 63;
    int wv = tid >> 6;
    int half = lane >> 5;
    int sl = lane & 31;
    int row = blockIdx.x * 8 + wv * 2 + half;
    int d0 = sl * 4;

    float4 av  = *(const float4*)(attl + d0);
    float4 bv  = *(const float4*)(bcl + d0);
    float4 xrv = *(const float4*)(xr + (size_t)row * H_ + d0);

    int jb = rowptr[row], je = rowptr[row + 1];
    int n = je - jb;
    int nother = __shfl_xor(n, 32);
    int nmax = n > nother ? n : nother;

    float m = -INFINITY, ssum = 0.f;
    float ac0 = 0, ac1 = 0, ac2 = 0, ac3 = 0;

    for (int i = 0; i < nmax; i++) {
        bool valid = i < n;
        int j = jb + (valid ? i : 0);
        int s = colarr[j];
        float4 v = *(const float4*)(xl + (size_t)s * H_ + d0);
        float t0 = v.x + xrv.x; t0 = t0 > 0.f ? t0 : NEG_ * t0;
        float t1 = v.y + xrv.y; t1 = t1 > 0.f ? t1 : NEG_ * t1;
        float t2 = v.z + xrv.z; t2 = t2 > 0.f ? t2 : NEG_ * t2;
        float t3 = v.w + xrv.w; t3 = t3 > 0.f ? t3 : NEG_ * t3;
        float p = av.x * t0 + av.y * t1 + av.z * t2 + av.w * t3;
        p += __shfl_xor(p, 16);
        p += __shfl_xor(p, 8);
        p += __shfl_xor(p, 4);
        p += __shfl_xor(p, 2);
        p += __shfl_xor(p, 1);
        if (!valid) p = -INFINITY;
        float nm = fmaxf(m, p);
        float sc  = __expf(m - nm);
        float wgt = __expf(p - nm);
        ssum = ssum * sc + wgt;
        ac0 = ac0 * sc + wgt * v.x;
        ac1 = ac1 * sc + wgt * v.y;
        ac2 = ac2 * sc + wgt * v.z;
        ac3 = ac3 * sc + wgt * v.w;
        m = nm;
    }
    float inv = 1.f / ssum;
    float4 o = { ac0 * inv + bv.x, ac1 * inv + bv.y, ac2 * inv + bv.z, ac3 * inv + bv.w };
    *(float4*)(h + (size_t)row * H_ + d0) = o;
}

// ---------------- GraphNorm (+ReLU, +pool) ----------------

__global__ void k_zero_gn(float* gmean, float* gvar) {
    int i = blockIdx.x * 256 + threadIdx.x;
    if (i < G_ * H_) { gmean[i] = 0.f; gvar[i] = 0.f; }
}

// 64 nodes per block; run-length accumulate per graph segment (batch sorted)
__global__ void k_gn_mean(const float* __restrict__ h, const int* __restrict__ batch, float* gmean) {
    int tid = threadIdx.x;
    int nb = blockIdx.x * 64;
    int d = tid & 127, hh = tid >> 7;
    int nend = nb + 64; if (nend > N_) nend = N_;
    float acc = 0.f; int curg = -1;
    for (int n = nb + hh; n < nend; n += 2) {
        int g = batch[n];
        if (g != curg) { if (curg >= 0) atomicAdd(&gmean[curg * H_ + d], acc); acc = 0.f; curg = g; }
        acc += h[(size_t)n * H_ + d];
    }
    if (curg >= 0) atomicAdd(&gmean[curg * H_ + d], acc);
}

__global__ void k_gn_finmean(float* gmean, const int* __restrict__ gstart) {
    int i = blockIdx.x * 256 + threadIdx.x;
    if (i < G_ * H_) {
        int g = i >> 7;
        int c = gstart[g + 1] - gstart[g]; if (c < 1) c = 1;
        gmean[i] /= (float)c;
    }
}

__global__ void k_gn_var(const float* __restrict__ h, const int* __restrict__ batch,
                         const float* __restrict__ gmean, const float* __restrict__ gnmsl, float* gvar) {
    int tid = threadIdx.x;
    int nb = blockIdx.x * 64;
    int d = tid & 127, hh = tid >> 7;
    int nend = nb + 64; if (nend > N_) nend = N_;
    float msd = gnmsl[d];
    float acc = 0.f; int curg = -1; float mv = 0.f;
    for (int n = nb + hh; n < nend; n += 2) {
        int g = batch[n];
        if (g != curg) {
            if (curg >= 0) atomicAdd(&gvar[curg * H_ + d], acc);
            acc = 0.f; curg = g; mv = msd * gmean[g * H_ + d];
        }
        float v = h[(size_t)n * H_ + d] - mv;
        acc += v * v;
    }
    if (curg >= 0) atomicAdd(&gvar[curg * H_ + d], acc);
}

__global__ void k_gn_finvar(float* gvar, const int* __restrict__ gstart, const float* __restrict__ gnwl) {
    int i = blockIdx.x * 256 + threadIdx.x;
    if (i < G_ * H_) {
        int g = i >> 7;
        int c = gstart[g + 1] - gstart[g]; if (c < 1) c = 1;
        float v = gvar[i] / (float)c;
        gvar[i] = gnwl[i & 127] * rsqrtf(v + EPS_);
    }
}

__global__ void k_gn_apply(float* __restrict__ h, const int* __restrict__ batch,
                           const float* __restrict__ gmean, const float* __restrict__ gvar,
                           const float* __restrict__ gnmsl, const float* __restrict__ gnbl,
                           float* pooled_l) {
    int tid = threadIdx.x;
    int nb = blockIdx.x * 64;
    int d = tid & 127, hh = tid >> 7;
    int nend = nb + 64; if (nend > N_) nend = N_;
    float msd = gnmsl[d], bb = gnbl[d];
    float pacc = 0.f; int curg = -1; float mv = 0.f, iv = 0.f;
    for (int n = nb + hh; n < nend; n += 2) {
        int g = batch[n];
        if (g != curg) {
            if (curg >= 0) atomicAdd(&pooled_l[curg * H_ + d], pacc);
            pacc = 0.f; curg = g;
            mv = msd * gmean[g * H_ + d];
            iv = gvar[g * H_ + d];
        }
        float v = (h[(size_t)n * H_ + d] - mv) * iv + bb;
        v = fmaxf(v, 0.f);
        h[(size_t)n * H_ + d] = v;
        pacc += v;
    }
    if (curg >= 0) atomicAdd(&pooled_l[curg * H_ + d], pacc);
}

// ---------------- final MLP ----------------

__global__ __launch_bounds__(128) void k_mlp(const float* __restrict__ pooled, const float* __restrict__ gfeat,
                                             const int* __restrict__ gstart,
                                             const float* __restrict__ W1, const float* __restrict__ b1,
                                             const float* __restrict__ W2, const float* __restrict__ b2,
                                             float* __restrict__ out) {
    int g = blockIdx.x;
    int c = threadIdx.x;
    __shared__ float hc[H_ * L_ + GD_];
    __shared__ float zz[H_];
    int cn = gstart[g + 1] - gstart[g]; if (cn < 1) cn = 1;
    float ic = 1.f / (float)cn;
    for (int k = c; k < H_ * L_; k += 128)
        hc[k] = pooled[(k >> 7) * G_ * H_ + g * H_ + (k & 127)] * ic;
    if (c < GD_) hc[H_ * L_ + c] = gfeat[g * GD_ + c];
    __syncthreads();
    float z = b1[c];
#pragma unroll 4
    for (int k = 0; k < H_ * L_ + GD_; k++)
        z += hc[k] * W1[k * H_ + c];
    z = fmaxf(z, 0.f);
    zz[c] = z * W2[c];
    __syncthreads();
    for (int off = 64; off > 0; off >>= 1) {
        if (c < off) zz[c] += zz[c + off];
        __syncthreads();
    }
    if (c == 0) out[g] = zz[0] + b2[0];
}

// ---------------- launch ----------------

extern "C" void kernel_launch(void* const* d_in, const int* in_sizes, int n_in,
                              void* d_out, int out_size, void* d_ws, size_t ws_size,
                              hipStream_t stream) {
    const float* x0    = (const float*)d_in[0];
    const float* gfeat = (const float*)d_in[1];
    const float* Wsrc  = (const float*)d_in[2];
    const float* Wdst  = (const float*)d_in[3];
    const float* att   = (const float*)d_in[4];
    const float* bconv = (const float*)d_in[5];
    const float* gnw   = (const float*)d_in[6];
    const float* gnb   = (const float*)d_in[7];
    const float* gnms  = (const float*)d_in[8];
    const float* W1    = (const float*)d_in[9];
    const float* b1    = (const float*)d_in[10];
    const float* W2    = (const float*)d_in[11];
    const float* b2    = (const float*)d_in[12];
    const int*   eidx  = (const int*)d_in[13];
    const int*   batch = (const int*)d_in[14];
    const int* esrc = eidx;
    const int* edst = eidx + E_;
    float* out = (float*)d_out;

    // workspace layout (256B aligned slabs)
    char* w = (char*)d_ws;
    size_t off = 0;
    auto alloc = [&](size_t bytes) { char* p = w + off; off += (bytes + 255) & ~(size_t)255; return p; };
    float* xl     = (float*)alloc((size_t)N_ * H_ * 4);
    float* xr     = (float*)alloc((size_t)N_ * H_ * 4);
    float* hbuf   = (float*)alloc((size_t)N_ * H_ * 4);
    int*   rowptr = (int*)alloc((size_t)(N_ + 1) * 4);
    int*   cursor = (int*)alloc((size_t)N_ * 4);
    int*   colarr = (int*)alloc((size_t)ETOT_ * 4);
    int*   bsum   = (int*)alloc(NSCAN * 4);
    int*   gstart = (int*)alloc((G_ + 1) * 4);
    float* gmean  = (float*)alloc(G_ * H_ * 4);
    float* gvar   = (float*)alloc(G_ * H_ * 4);
    float* pooled = (float*)alloc((size_t)L_ * G_ * H_ * 4);
    (void)ws_size; (void)in_sizes; (void)n_in; (void)out_size;

    // CSR build (dst-indexed, includes self-loops)
    k_init<<<(N_ + 255) / 256, 256, 0, stream>>>(cursor, pooled, gstart, batch);
    k_hist<<<(E_ + 255) / 256, 256, 0, stream>>>(edst, cursor);
    k_scan1<<<NSCAN, 256, 0, stream>>>(cursor, rowptr, bsum);
    k_scan2<<<1, 64, 0, stream>>>(bsum);
    k_scan3<<<(N_ + 255) / 256, 256, 0, stream>>>(rowptr, cursor, bsum);
    k_scatter<<<(E_ + N_ + 255) / 256, 256, 0, stream>>>(esrc, edst, cursor, colarr);

    for (int l = 0; l < L_; l++) {
        const float* xin = (l == 0) ? x0 : hbuf;
        k_gemm<<<N_ / 32, 256, 0, stream>>>(xin, Wsrc + (size_t)l * H_ * H_, xl);
        k_gemm<<<N_ / 32, 256, 0, stream>>>(xin, Wdst + (size_t)l * H_ * H_, xr);
        k_conv<<<N_ / 8, 256, 0, stream>>>(xl, xr, rowptr, colarr,
                                           att + (size_t)l * H_, bconv + (size_t)l * H_, hbuf);
        k_zero_gn<<<(G_ * H_ + 255) / 256, 256, 0, stream>>>(gmean, gvar);
        k_gn_mean<<<(N_ + 63) / 64, 256, 0, stream>>>(hbuf, batch, gmean);
        k_gn_finmean<<<(G_ * H_ + 255) / 256, 256, 0, stream>>>(gmean, gstart);
        k_gn_var<<<(N_ + 63) / 64, 256, 0, stream>>>(hbuf, batch, gmean, gnms + (size_t)l * H_, gvar);
        k_gn_finvar<<<(G_ * H_ + 255) / 256, 256, 0, stream>>>(gvar, gstart, gnw + (size_t)l * H_);
        k_gn_apply<<<(N_ + 63) / 64, 256, 0, stream>>>(hbuf, batch, gmean, gvar,
                                                       gnms + (size_t)l * H_, gnb + (size_t)l * H_,
                                                       pooled + (size_t)l * G_ * H_);
    }

    k_mlp<<<G_, 128, 0, stream>>>(pooled, gfeat, gstart, W1, b1, W2, b2, out);
}

// Round 2
// 1093.805 us; speedup vs baseline: 1.2175x; 1.2175x over previous
//
#include <hip/hip_runtime.h>
#include <hip/hip_bf16.h>
#include <math.h>

#define N_    100000
#define E_    1600000
#define ETOT_ 1700000   // E + N self-loops
#define G_    64
#define H_    128
#define L_    3
#define GD_   32
#define NEG_  0.2f
#define EPS_  1e-5f

#define SCAN_B 2048
#define NSCAN  49       // ceil(N_/SCAN_B)

#define BM_ 64
#define KC_ 32

typedef unsigned short ushort_t;
typedef unsigned int uint_t;

__device__ __forceinline__ uint_t pack_bf2(float a, float b) {
    __hip_bfloat16 ba = __float2bfloat16(a);
    __hip_bfloat16 bb = __float2bfloat16(b);
    ushort_t ua = *reinterpret_cast<ushort_t*>(&ba);
    ushort_t ub = *reinterpret_cast<ushort_t*>(&bb);
    return (uint_t)ua | ((uint_t)ub << 16);
}

// ---------------- CSR build ----------------

__global__ void k_init(int* cursor, float* pooled, int* gstart, const int* __restrict__ batch) {
    int i = blockIdx.x * 256 + threadIdx.x;
    if (i < N_) cursor[i] = 1;                 // deg starts at 1 (self-loop)
    if (i < L_ * G_ * H_) pooled[i] = 0.f;
    if (i <= G_) {
        int lo = 0, hi = N_;
        while (lo < hi) { int mid = (lo + hi) >> 1; if (batch[mid] < i) lo = mid + 1; else hi = mid; }
        gstart[i] = lo;
    }
}

__global__ void k_hist(const int* __restrict__ edst, int* cursor) {
    int i = blockIdx.x * 256 + threadIdx.x;
    if (i < E_) atomicAdd(&cursor[edst[i]], 1);
}

__global__ __launch_bounds__(256) void k_scan1(const int* __restrict__ deg, int* out, int* bsum) {
    __shared__ int lds[SCAN_B];
    __shared__ int tsum[256];
    int t = threadIdx.x, b = blockIdx.x;
    int base = b * SCAN_B;
    for (int i = t; i < SCAN_B; i += 256) lds[i] = (base + i < N_) ? deg[base + i] : 0;
    __syncthreads();
    int o = t * 8;
    int v[8]; int run = 0;
#pragma unroll
    for (int i = 0; i < 8; i++) { int x = lds[o + i]; v[i] = run; run += x; }
    tsum[t] = run;
    __syncthreads();
    for (int off = 1; off < 256; off <<= 1) {
        int x = (t >= off) ? tsum[t - off] : 0;
        __syncthreads();
        tsum[t] += x;
        __syncthreads();
    }
    int excl = tsum[t] - run;
#pragma unroll
    for (int i = 0; i < 8; i++) lds[o + i] = v[i] + excl;
    __syncthreads();
    for (int i = t; i < SCAN_B; i += 256) if (base + i < N_) out[base + i] = lds[i];
    if (t == 255) bsum[b] = tsum[255];
}

__global__ void k_scan2(int* bsum) {
    if (threadIdx.x == 0) {
        int run = 0;
        for (int i = 0; i < NSCAN; i++) { int x = bsum[i]; bsum[i] = run; run += x; }
    }
}

__global__ void k_scan3(int* rowptr, int* cursor, const int* __restrict__ bsum) {
    int i = blockIdx.x * 256 + threadIdx.x;
    if (i < N_) {
        int v = rowptr[i] + bsum[i >> 11];
        rowptr[i] = v;
        cursor[i] = v;
    }
    if (i == 0) rowptr[N_] = ETOT_;
}

__global__ void k_scatter(const int* __restrict__ esrc, const int* __restrict__ edst,
                          int* cursor, int* __restrict__ colarr) {
    int i = blockIdx.x * 256 + threadIdx.x;
    if (i >= E_ + N_) return;
    int s, d;
    if (i < E_) { s = esrc[i]; d = edst[i]; } else { s = d = i - E_; }
    int pos = atomicAdd(&cursor[d], 1);
    colarr[pos] = s;
}

// ---------------- fused GEMM: xl_bf16[N,128] = x@Wsrc (bf16), xr[N,128] = x@Wdst (f32) ----------------
// block: 64 rows x 256 cols (128 src + 128 dst), 256 threads, 8x8 acc/thread.

__global__ __launch_bounds__(256) void k_gemm2(const float* __restrict__ x,
                                               const float* __restrict__ Ws,
                                               const float* __restrict__ Wd,
                                               ushort_t* __restrict__ xlb,
                                               float* __restrict__ xr) {
    __shared__ float sx[BM_ * KC_];    // [row][kk]  8 KB
    __shared__ float sw[KC_ * 256];    // [kk][c]   32 KB
    int tid = threadIdx.x;
    int base = blockIdx.x * BM_;
    int tx = tid & 31, ty = tid >> 5;

    float acc[8][8];
#pragma unroll
    for (int i = 0; i < 8; i++)
#pragma unroll
        for (int j = 0; j < 8; j++) acc[i][j] = 0.f;

#pragma unroll 1
    for (int kc = 0; kc < H_ / KC_; kc++) {
        __syncthreads();
        // x tile: 64 rows x 32 k (512 float4, 2/thread)
#pragma unroll
        for (int j = 0; j < 2; j++) {
            int idx = tid + j * 256;
            int rr = idx >> 3, cc = (idx & 7) * 4;
            int r = base + rr; if (r >= N_) r = N_ - 1;
            float4 v = *(const float4*)(x + (size_t)r * H_ + kc * KC_ + cc);
            *(float4*)(sx + rr * KC_ + cc) = v;
        }
        // W tile: 32 kk x 256 c (2048 float4, 8/thread)
#pragma unroll
        for (int j = 0; j < 8; j++) {
            int idx = tid + j * 256;
            int kk = idx >> 6, c4 = (idx & 63) * 4;
            const float* srcp = (c4 < 128) ? (Ws + (size_t)(kc * KC_ + kk) * H_ + c4)
                                           : (Wd + (size_t)(kc * KC_ + kk) * H_ + (c4 - 128));
            *(float4*)(sw + kk * 256 + c4) = *(const float4*)srcp;
        }
        __syncthreads();
#pragma unroll 4
        for (int kk = 0; kk < KC_; kk++) {
            float xv[8];
#pragma unroll
            for (int i = 0; i < 8; i++) xv[i] = sx[(ty * 8 + i) * KC_ + kk];
            const float4 wa = *(const float4*)(sw + kk * 256 + tx * 8);
            const float4 wb = *(const float4*)(sw + kk * 256 + tx * 8 + 4);
#pragma unroll
            for (int i = 0; i < 8; i++) {
                acc[i][0] = fmaf(xv[i], wa.x, acc[i][0]);
                acc[i][1] = fmaf(xv[i], wa.y, acc[i][1]);
                acc[i][2] = fmaf(xv[i], wa.z, acc[i][2]);
                acc[i][3] = fmaf(xv[i], wa.w, acc[i][3]);
                acc[i][4] = fmaf(xv[i], wb.x, acc[i][4]);
                acc[i][5] = fmaf(xv[i], wb.y, acc[i][5]);
                acc[i][6] = fmaf(xv[i], wb.z, acc[i][6]);
                acc[i][7] = fmaf(xv[i], wb.w, acc[i][7]);
            }
        }
    }

    if (tx < 16) {
        int c0 = tx * 8;
#pragma unroll
        for (int i = 0; i < 8; i++) {
            int r = base + ty * 8 + i;
            if (r < N_) {
                uint4 o;
                o.x = pack_bf2(acc[i][0], acc[i][1]);
                o.y = pack_bf2(acc[i][2], acc[i][3]);
                o.z = pack_bf2(acc[i][4], acc[i][5]);
                o.w = pack_bf2(acc[i][6], acc[i][7]);
                *(uint4*)(xlb + (size_t)r * H_ + c0) = o;
            }
        }
    } else {
        int c0 = (tx - 16) * 8;
#pragma unroll
        for (int i = 0; i < 8; i++) {
            int r = base + ty * 8 + i;
            if (r < N_) {
                float4 va = { acc[i][0], acc[i][1], acc[i][2], acc[i][3] };
                float4 vb = { acc[i][4], acc[i][5], acc[i][6], acc[i][7] };
                *(float4*)(xr + (size_t)r * H_ + c0) = va;
                *(float4*)(xr + (size_t)r * H_ + c0 + 4) = vb;
            }
        }
    }
}

// ---------------- GATv2 conv: per-dst online softmax + aggregate ----------------
// 32 lanes per dst row (4 dims/lane), 2 rows per wave, 8 rows per block.
// xl gathered as bf16 (half the bytes).

__global__ __launch_bounds__(256) void k_conv(const ushort_t* __restrict__ xlb, const float* __restrict__ xr,
                                              const int* __restrict__ rowptr, const int* __restrict__ colarr,
                                              const float* __restrict__ attl, const float* __restrict__ bcl,
                                              float* __restrict__ h) {
    int tid = threadIdx.x;
    int lane = tid & 63;
    int wv = tid >> 6;
    int half = lane >> 5;
    int sl = lane & 31;
    int row = blockIdx.x * 8 + wv * 2 + half;
    int d0 = sl * 4;

    float4 av  = *(const float4*)(attl + d0);
    float4 bv  = *(const float4*)(bcl + d0);
    float4 xrv = *(const float4*)(xr + (size_t)row * H_ + d0);

    int jb = rowptr[row], je = rowptr[row + 1];
    int n = je - jb;
    int nother = __shfl_xor(n, 32);
    int nmax = n > nother ? n : nother;

    float m = -INFINITY, ssum = 0.f;
    float ac0 = 0, ac1 = 0, ac2 = 0, ac3 = 0;

    for (int i = 0; i < nmax; i++) {
        bool valid = i < n;
        int j = jb + (valid ? i : 0);
        int s = colarr[j];
        ushort4 u = *(const ushort4*)(xlb + (size_t)s * H_ + d0);
        float vx = __uint_as_float(((uint_t)u.x) << 16);
        float vy = __uint_as_float(((uint_t)u.y) << 16);
        float vz = __uint_as_float(((uint_t)u.z) << 16);
        float vw = __uint_as_float(((uint_t)u.w) << 16);
        float t0 = vx + xrv.x; t0 = t0 > 0.f ? t0 : NEG_ * t0;
        float t1 = vy + xrv.y; t1 = t1 > 0.f ? t1 : NEG_ * t1;
        float t2 = vz + xrv.z; t2 = t2 > 0.f ? t2 : NEG_ * t2;
        float t3 = vw + xrv.w; t3 = t3 > 0.f ? t3 : NEG_ * t3;
        float p = av.x * t0 + av.y * t1 + av.z * t2 + av.w * t3;
        p += __shfl_xor(p, 16);
        p += __shfl_xor(p, 8);
        p += __shfl_xor(p, 4);
        p += __shfl_xor(p, 2);
        p += __shfl_xor(p, 1);
        if (!valid) p = -INFINITY;
        float nm = fmaxf(m, p);
        float sc  = __expf(m - nm);
        float wgt = __expf(p - nm);
        ssum = ssum * sc + wgt;
        ac0 = ac0 * sc + wgt * vx;
        ac1 = ac1 * sc + wgt * vy;
        ac2 = ac2 * sc + wgt * vz;
        ac3 = ac3 * sc + wgt * vw;
        m = nm;
    }
    float inv = 1.f / ssum;
    float4 o = { ac0 * inv + bv.x, ac1 * inv + bv.y, ac2 * inv + bv.z, ac3 * inv + bv.w };
    *(float4*)(h + (size_t)row * H_ + d0) = o;
}

// ---------------- GraphNorm (+ReLU, +pool) ----------------

__global__ void k_zero_gn(float* gsum, float* gsq) {
    int i = blockIdx.x * 256 + threadIdx.x;
    if (i < G_ * H_) { gsum[i] = 0.f; gsq[i] = 0.f; }
}

// 64 nodes per block; run-length accumulate sum + sumsq per graph segment (batch sorted)
__global__ void k_gn_stat(const float* __restrict__ h, const int* __restrict__ batch,
                          float* gsum, float* gsq) {
    int tid = threadIdx.x;
    int nb = blockIdx.x * 64;
    int d = tid & 127, hh = tid >> 7;
    int nend = nb + 64; if (nend > N_) nend = N_;
    float s1 = 0.f, s2 = 0.f; int curg = -1;
    for (int n = nb + hh; n < nend; n += 2) {
        int g = batch[n];
        if (g != curg) {
            if (curg >= 0) { atomicAdd(&gsum[curg * H_ + d], s1); atomicAdd(&gsq[curg * H_ + d], s2); }
            s1 = 0.f; s2 = 0.f; curg = g;
        }
        float v = h[(size_t)n * H_ + d];
        s1 += v; s2 += v * v;
    }
    if (curg >= 0) { atomicAdd(&gsum[curg * H_ + d], s1); atomicAdd(&gsq[curg * H_ + d], s2); }
}

// gsum -> mv = ms*mean ; gsq -> iv = gn_w * rsqrt(var + eps)
__global__ void k_gn_fin(float* gsum, float* gsq, const int* __restrict__ gstart,
                         const float* __restrict__ gnwl, const float* __restrict__ gnmsl) {
    int i = blockIdx.x * 256 + threadIdx.x;
    if (i < G_ * H_) {
        int g = i >> 7, d = i & 127;
        int c = gstart[g + 1] - gstart[g]; if (c < 1) c = 1;
        float ic = 1.f / (float)c;
        float mean = gsum[i] * ic;
        float e2   = gsq[i] * ic;
        float ms = gnmsl[d];
        float var = e2 - ms * (2.f - ms) * mean * mean;
        gsum[i] = ms * mean;
        gsq[i]  = gnwl[d] * rsqrtf(var + EPS_);
    }
}

__global__ void k_gn_apply(float* __restrict__ h, const int* __restrict__ batch,
                           const float* __restrict__ gmv, const float* __restrict__ giv,
                           const float* __restrict__ gnbl,
                           float* pooled_l) {
    int tid = threadIdx.x;
    int nb = blockIdx.x * 64;
    int d = tid & 127, hh = tid >> 7;
    int nend = nb + 64; if (nend > N_) nend = N_;
    float bb = gnbl[d];
    float pacc = 0.f; int curg = -1; float mv = 0.f, iv = 0.f;
    for (int n = nb + hh; n < nend; n += 2) {
        int g = batch[n];
        if (g != curg) {
            if (curg >= 0) atomicAdd(&pooled_l[curg * H_ + d], pacc);
            pacc = 0.f; curg = g;
            mv = gmv[g * H_ + d];
            iv = giv[g * H_ + d];
        }
        float v = (h[(size_t)n * H_ + d] - mv) * iv + bb;
        v = fmaxf(v, 0.f);
        h[(size_t)n * H_ + d] = v;
        pacc += v;
    }
    if (curg >= 0) atomicAdd(&pooled_l[curg * H_ + d], pacc);
}

// ---------------- final MLP ----------------

__global__ __launch_bounds__(128) void k_mlp(const float* __restrict__ pooled, const float* __restrict__ gfeat,
                                             const int* __restrict__ gstart,
                                             const float* __restrict__ W1, const float* __restrict__ b1,
                                             const float* __restrict__ W2, const float* __restrict__ b2,
                                             float* __restrict__ out) {
    int g = blockIdx.x;
    int c = threadIdx.x;
    __shared__ float hc[H_ * L_ + GD_];
    __shared__ float zz[H_];
    int cn = gstart[g + 1] - gstart[g]; if (cn < 1) cn = 1;
    float ic = 1.f / (float)cn;
    for (int k = c; k < H_ * L_; k += 128)
        hc[k] = pooled[(k >> 7) * G_ * H_ + g * H_ + (k & 127)] * ic;
    if (c < GD_) hc[H_ * L_ + c] = gfeat[g * GD_ + c];
    __syncthreads();
    float z = b1[c];
#pragma unroll 4
    for (int k = 0; k < H_ * L_ + GD_; k++)
        z += hc[k] * W1[k * H_ + c];
    z = fmaxf(z, 0.f);
    zz[c] = z * W2[c];
    __syncthreads();
    for (int off = 64; off > 0; off >>= 1) {
        if (c < off) zz[c] += zz[c + off];
        __syncthreads();
    }
    if (c == 0) out[g] = zz[0] + b2[0];
}

// ---------------- launch ----------------

extern "C" void kernel_launch(void* const* d_in, const int* in_sizes, int n_in,
                              void* d_out, int out_size, void* d_ws, size_t ws_size,
                              hipStream_t stream) {
    const float* x0    = (const float*)d_in[0];
    const float* gfeat = (const float*)d_in[1];
    const float* Wsrc  = (const float*)d_in[2];
    const float* Wdst  = (const float*)d_in[3];
    const float* att   = (const float*)d_in[4];
    const float* bconv = (const float*)d_in[5];
    const float* gnw   = (const float*)d_in[6];
    const float* gnb   = (const float*)d_in[7];
    const float* gnms  = (const float*)d_in[8];
    const float* W1    = (const float*)d_in[9];
    const float* b1    = (const float*)d_in[10];
    const float* W2    = (const float*)d_in[11];
    const float* b2    = (const float*)d_in[12];
    const int*   eidx  = (const int*)d_in[13];
    const int*   batch = (const int*)d_in[14];
    const int* esrc = eidx;
    const int* edst = eidx + E_;
    float* out = (float*)d_out;

    char* w = (char*)d_ws;
    size_t off = 0;
    auto alloc = [&](size_t bytes) { char* p = w + off; off += (bytes + 255) & ~(size_t)255; return p; };
    ushort_t* xlb   = (ushort_t*)alloc((size_t)N_ * H_ * 2);
    float* xr     = (float*)alloc((size_t)N_ * H_ * 4);
    float* hbuf   = (float*)alloc((size_t)N_ * H_ * 4);
    int*   rowptr = (int*)alloc((size_t)(N_ + 1) * 4);
    int*   cursor = (int*)alloc((size_t)N_ * 4);
    int*   colarr = (int*)alloc((size_t)ETOT_ * 4);
    int*   bsum   = (int*)alloc(NSCAN * 4);
    int*   gstart = (int*)alloc((G_ + 1) * 4);
    float* gsum   = (float*)alloc(G_ * H_ * 4);
    float* gsq    = (float*)alloc(G_ * H_ * 4);
    float* pooled = (float*)alloc((size_t)L_ * G_ * H_ * 4);
    (void)ws_size; (void)in_sizes; (void)n_in; (void)out_size;

    // CSR build (dst-indexed, includes self-loops)
    k_init<<<(N_ + 255) / 256, 256, 0, stream>>>(cursor, pooled, gstart, batch);
    k_hist<<<(E_ + 255) / 256, 256, 0, stream>>>(edst, cursor);
    k_scan1<<<NSCAN, 256, 0, stream>>>(cursor, rowptr, bsum);
    k_scan2<<<1, 64, 0, stream>>>(bsum);
    k_scan3<<<(N_ + 255) / 256, 256, 0, stream>>>(rowptr, cursor, bsum);
    k_scatter<<<(E_ + N_ + 255) / 256, 256, 0, stream>>>(esrc, edst, cursor, colarr);

    int gemm_grid = (N_ + BM_ - 1) / BM_;
    for (int l = 0; l < L_; l++) {
        const float* xin = (l == 0) ? x0 : hbuf;
        k_gemm2<<<gemm_grid, 256, 0, stream>>>(xin, Wsrc + (size_t)l * H_ * H_,
                                               Wdst + (size_t)l * H_ * H_, xlb, xr);
        k_conv<<<N_ / 8, 256, 0, stream>>>(xlb, xr, rowptr, colarr,
                                           att + (size_t)l * H_, bconv + (size_t)l * H_, hbuf);
        k_zero_gn<<<(G_ * H_ + 255) / 256, 256, 0, stream>>>(gsum, gsq);
        k_gn_stat<<<(N_ + 63) / 64, 256, 0, stream>>>(hbuf, batch, gsum, gsq);
        k_gn_fin<<<(G_ * H_ + 255) / 256, 256, 0, stream>>>(gsum, gsq, gstart,
                                                            gnw + (size_t)l * H_, gnms + (size_t)l * H_);
        k_gn_apply<<<(N_ + 63) / 64, 256, 0, stream>>>(hbuf, batch, gsum, gsq,
                                                       gnb + (size_t)l * H_,
                                                       pooled + (size_t)l * G_ * H_);
    }

    k_mlp<<<G_, 128, 0, stream>>>(pooled, gfeat, gstart, W1, b1, W2, b2, out);
}

// Round 3
// 797.034 us; speedup vs baseline: 1.6708x; 1.3723x over previous
//
#include <hip/hip_runtime.h>
#include <hip/hip_bf16.h>
#include <math.h>

#define N_    100000
#define E_    1600000
#define ETOT_ 1700000   // E + N self-loops
#define G_    64
#define H_    128
#define L_    3
#define GD_   32
#define NEG_  0.2f
#define EPS_  1e-5f

#define SCAN_B 2048
#define NSCAN  49       // ceil(N_/SCAN_B)

typedef unsigned short ushort_t;
typedef unsigned int uint_t;
typedef __attribute__((ext_vector_type(4))) float f32x4;
typedef __attribute__((ext_vector_type(8))) short bf16x8;
typedef __attribute__((ext_vector_type(8))) unsigned short ushort8;

__device__ __forceinline__ ushort_t bfb(float f) {
    __hip_bfloat16 h = __float2bfloat16(f);
    return *reinterpret_cast<ushort_t*>(&h);
}

// ---------------- CSR build ----------------

__global__ void k_init(int* cursor, float* pooled, int* gstart, const int* __restrict__ batch) {
    int i = blockIdx.x * 256 + threadIdx.x;
    if (i < N_) cursor[i] = 1;                 // deg starts at 1 (self-loop)
    if (i < L_ * G_ * H_) pooled[i] = 0.f;
    if (i <= G_) {
        int lo = 0, hi = N_;
        while (lo < hi) { int mid = (lo + hi) >> 1; if (batch[mid] < i) lo = mid + 1; else hi = mid; }
        gstart[i] = lo;
    }
}

__global__ void k_hist(const int* __restrict__ edst, int* cursor) {
    int i = blockIdx.x * 256 + threadIdx.x;
    if (i < E_) atomicAdd(&cursor[edst[i]], 1);
}

__global__ __launch_bounds__(256) void k_scan1(const int* __restrict__ deg, int* out, int* bsum) {
    __shared__ int lds[SCAN_B];
    __shared__ int tsum[256];
    int t = threadIdx.x, b = blockIdx.x;
    int base = b * SCAN_B;
    for (int i = t; i < SCAN_B; i += 256) lds[i] = (base + i < N_) ? deg[base + i] : 0;
    __syncthreads();
    int o = t * 8;
    int v[8]; int run = 0;
#pragma unroll
    for (int i = 0; i < 8; i++) { int x = lds[o + i]; v[i] = run; run += x; }
    tsum[t] = run;
    __syncthreads();
    for (int off = 1; off < 256; off <<= 1) {
        int x = (t >= off) ? tsum[t - off] : 0;
        __syncthreads();
        tsum[t] += x;
        __syncthreads();
    }
    int excl = tsum[t] - run;
#pragma unroll
    for (int i = 0; i < 8; i++) lds[o + i] = v[i] + excl;
    __syncthreads();
    for (int i = t; i < SCAN_B; i += 256) if (base + i < N_) out[base + i] = lds[i];
    if (t == 255) bsum[b] = tsum[255];
}

__global__ void k_scan2(int* bsum) {
    if (threadIdx.x == 0) {
        int run = 0;
        for (int i = 0; i < NSCAN; i++) { int x = bsum[i]; bsum[i] = run; run += x; }
    }
}

__global__ void k_scan3(int* rowptr, int* cursor, const int* __restrict__ bsum) {
    int i = blockIdx.x * 256 + threadIdx.x;
    if (i < N_) {
        int v = rowptr[i] + bsum[i >> 11];
        rowptr[i] = v;
        cursor[i] = v;
    }
    if (i == 0) rowptr[N_] = ETOT_;
}

__global__ void k_scatter(const int* __restrict__ esrc, const int* __restrict__ edst,
                          int* cursor, int* __restrict__ colarr) {
    int i = blockIdx.x * 256 + threadIdx.x;
    if (i >= E_ + N_) return;
    int s, d;
    if (i < E_) { s = esrc[i]; d = edst[i]; } else { s = d = i - E_; }
    int pos = atomicAdd(&cursor[d], 1);
    colarr[pos] = s;
}

// ---------------- bf16 conversions ----------------

__global__ void k_cvt(const float* __restrict__ x, ushort_t* __restrict__ xb) {
    int i = blockIdx.x * 256 + threadIdx.x;   // one float4 per thread
    float4 v = *(const float4*)(x + (size_t)i * 4);
    ushort4 o;
    o.x = bfb(v.x); o.y = bfb(v.y); o.z = bfb(v.z); o.w = bfb(v.w);
    *(ushort4*)(xb + (size_t)i * 4) = o;
}

// Wt[l][c][k] = bf16( c<128 ? Ws[l][k][c] : Wd[l][k][c-128] )
__global__ void k_prep_w(const float* __restrict__ Ws, const float* __restrict__ Wd,
                         ushort_t* __restrict__ Wt) {
    int i = blockIdx.x * 256 + threadIdx.x;
    if (i >= L_ * 256 * H_) return;
    int l = i >> 15;
    int r = i & 32767;
    int c = r >> 7, k = r & 127;
    float v = (c < H_) ? Ws[(size_t)l * H_ * H_ + k * H_ + c]
                       : Wd[(size_t)l * H_ * H_ + k * H_ + (c - H_)];
    Wt[i] = bfb(v);
}

// ---------------- MFMA GEMM: [N,128]bf16 @ [128,256]bf16 -> xlb bf16 [N,128], xr f32 [N,128] ----------------
// wave computes 16 rows x 256 cols; no LDS; Wt is L2-resident.

__global__ __launch_bounds__(256) void k_mfma(const ushort_t* __restrict__ xb,
                                              const ushort_t* __restrict__ Wt,
                                              ushort_t* __restrict__ xlb,
                                              float* __restrict__ xr) {
    int wv = threadIdx.x >> 6, lane = threadIdx.x & 63;
    int wt = blockIdx.x * 4 + wv;
    int row0 = wt * 16;
    if (row0 >= N_) return;
    int sl = lane & 15, q = lane >> 4;

    bf16x8 a[4];
    const ushort_t* ap = xb + (size_t)(row0 + sl) * H_ + q * 8;
#pragma unroll
    for (int kk = 0; kk < 4; kk++) a[kk] = *(const bf16x8*)(ap + kk * 32);

    f32x4 acc[16];
#pragma unroll
    for (int c = 0; c < 16; c++) acc[c] = (f32x4){0.f, 0.f, 0.f, 0.f};

#pragma unroll
    for (int c = 0; c < 16; c++) {
        const ushort_t* bp = Wt + (size_t)(c * 16 + sl) * H_ + q * 8;
#pragma unroll
        for (int kk = 0; kk < 4; kk++) {
            bf16x8 b = *(const bf16x8*)(bp + kk * 32);
            acc[c] = __builtin_amdgcn_mfma_f32_16x16x32_bf16(a[kk], b, acc[c], 0, 0, 0);
        }
    }

    int orow = row0 + q * 4;
#pragma unroll
    for (int c = 0; c < 8; c++)
#pragma unroll
        for (int j = 0; j < 4; j++)
            xlb[(size_t)(orow + j) * H_ + c * 16 + sl] = bfb(acc[c][j]);
#pragma unroll
    for (int c = 8; c < 16; c++)
#pragma unroll
        for (int j = 0; j < 4; j++)
            xr[(size_t)(orow + j) * H_ + (c - 8) * 16 + sl] = acc[c][j];
}

// ---------------- GATv2 conv: 16 lanes x 8 dims per dst row, no-max softmax ----------------

__global__ __launch_bounds__(256) void k_conv(const ushort_t* __restrict__ xlb, const float* __restrict__ xr,
                                              const int* __restrict__ rowptr, const int* __restrict__ colarr,
                                              const float* __restrict__ attl, const float* __restrict__ bcl,
                                              float* __restrict__ h) {
    int tid = threadIdx.x;
    int lane = tid & 63, wv = tid >> 6;
    int sl = lane & 15, q = lane >> 4;
    int row = blockIdx.x * 16 + wv * 4 + q;
    int d0 = sl * 8;

    float xrv[8], av[8], av5[8];
    {
        float4 t0 = *(const float4*)(xr + (size_t)row * H_ + d0);
        float4 t1 = *(const float4*)(xr + (size_t)row * H_ + d0 + 4);
        xrv[0] = t0.x; xrv[1] = t0.y; xrv[2] = t0.z; xrv[3] = t0.w;
        xrv[4] = t1.x; xrv[5] = t1.y; xrv[6] = t1.z; xrv[7] = t1.w;
        float4 a0 = *(const float4*)(attl + d0);
        float4 a1 = *(const float4*)(attl + d0 + 4);
        av[0] = a0.x; av[1] = a0.y; av[2] = a0.z; av[3] = a0.w;
        av[4] = a1.x; av[5] = a1.y; av[6] = a1.z; av[7] = a1.w;
#pragma unroll
        for (int e = 0; e < 8; e++) av5[e] = NEG_ * av[e];
    }

    int jb = rowptr[row];
    int n = rowptr[row + 1] - jb;

    float ssum = 0.f;
    float ac[8] = {0.f, 0.f, 0.f, 0.f, 0.f, 0.f, 0.f, 0.f};

    int s = (n > 0) ? colarr[jb] : 0;
    for (int i = 0; i < n; i++) {
        int snext = (i + 1 < n) ? colarr[jb + i + 1] : 0;
        ushort8 u = *(const ushort8*)(xlb + (size_t)s * H_ + d0);
        float v[8];
        float p = 0.f;
#pragma unroll
        for (int e = 0; e < 8; e++) {
            v[e] = __uint_as_float(((uint_t)u[e]) << 16);
            float t = v[e] + xrv[e];
            p = fmaf(t, (t > 0.f ? av[e] : av5[e]), p);
        }
        p += __shfl_xor(p, 8);
        p += __shfl_xor(p, 4);
        p += __shfl_xor(p, 2);
        p += __shfl_xor(p, 1);
        float wgt = __expf(p);
        ssum += wgt;
#pragma unroll
        for (int e = 0; e < 8; e++) ac[e] = fmaf(wgt, v[e], ac[e]);
        s = snext;
    }

    float inv = 1.f / ssum;
    float4 b0 = *(const float4*)(bcl + d0);
    float4 b1 = *(const float4*)(bcl + d0 + 4);
    float4 o0 = { ac[0] * inv + b0.x, ac[1] * inv + b0.y, ac[2] * inv + b0.z, ac[3] * inv + b0.w };
    float4 o1 = { ac[4] * inv + b1.x, ac[5] * inv + b1.y, ac[6] * inv + b1.z, ac[7] * inv + b1.w };
    *(float4*)(h + (size_t)row * H_ + d0) = o0;
    *(float4*)(h + (size_t)row * H_ + d0 + 4) = o1;
}

// ---------------- GraphNorm (+ReLU, +pool) ----------------

__global__ void k_zero_gn(float* gsum, float* gsq) {
    int i = blockIdx.x * 256 + threadIdx.x;
    if (i < G_ * H_) { gsum[i] = 0.f; gsq[i] = 0.f; }
}

__global__ void k_gn_stat(const float* __restrict__ h, const int* __restrict__ batch,
                          float* gsum, float* gsq) {
    int tid = threadIdx.x;
    int nb = blockIdx.x * 64;
    int d = tid & 127, hh = tid >> 7;
    int nend = nb + 64; if (nend > N_) nend = N_;
    float s1 = 0.f, s2 = 0.f; int curg = -1;
    for (int n = nb + hh; n < nend; n += 2) {
        int g = batch[n];
        if (g != curg) {
            if (curg >= 0) { atomicAdd(&gsum[curg * H_ + d], s1); atomicAdd(&gsq[curg * H_ + d], s2); }
            s1 = 0.f; s2 = 0.f; curg = g;
        }
        float v = h[(size_t)n * H_ + d];
        s1 += v; s2 += v * v;
    }
    if (curg >= 0) { atomicAdd(&gsum[curg * H_ + d], s1); atomicAdd(&gsq[curg * H_ + d], s2); }
}

// gsum -> mv = ms*mean ; gsq -> iv = gn_w * rsqrt(var + eps)
__global__ void k_gn_fin(float* gsum, float* gsq, const int* __restrict__ gstart,
                         const float* __restrict__ gnwl, const float* __restrict__ gnmsl) {
    int i = blockIdx.x * 256 + threadIdx.x;
    if (i < G_ * H_) {
        int g = i >> 7, d = i & 127;
        int c = gstart[g + 1] - gstart[g]; if (c < 1) c = 1;
        float ic = 1.f / (float)c;
        float mean = gsum[i] * ic;
        float e2   = gsq[i] * ic;
        float ms = gnmsl[d];
        float var = e2 - ms * (2.f - ms) * mean * mean;
        gsum[i] = ms * mean;
        gsq[i]  = gnwl[d] * rsqrtf(var + EPS_);
    }
}

// apply + relu + pool; writes next-layer GEMM input as bf16
__global__ void k_gn_apply(const float* __restrict__ h, const int* __restrict__ batch,
                           const float* __restrict__ gmv, const float* __restrict__ giv,
                           const float* __restrict__ gnbl,
                           ushort_t* __restrict__ hb, float* pooled_l) {
    int tid = threadIdx.x;
    int nb = blockIdx.x * 64;
    int d = tid & 127, hh = tid >> 7;
    int nend = nb + 64; if (nend > N_) nend = N_;
    float bb = gnbl[d];
    float pacc = 0.f; int curg = -1; float mv = 0.f, iv = 0.f;
    for (int n = nb + hh; n < nend; n += 2) {
        int g = batch[n];
        if (g != curg) {
            if (curg >= 0) atomicAdd(&pooled_l[curg * H_ + d], pacc);
            pacc = 0.f; curg = g;
            mv = gmv[g * H_ + d];
            iv = giv[g * H_ + d];
        }
        float v = (h[(size_t)n * H_ + d] - mv) * iv + bb;
        v = fmaxf(v, 0.f);
        hb[(size_t)n * H_ + d] = bfb(v);
        pacc += v;
    }
    if (curg >= 0) atomicAdd(&pooled_l[curg * H_ + d], pacc);
}

// ---------------- final MLP ----------------

__global__ __launch_bounds__(128) void k_mlp(const float* __restrict__ pooled, const float* __restrict__ gfeat,
                                             const int* __restrict__ gstart,
                                             const float* __restrict__ W1, const float* __restrict__ b1,
                                             const float* __restrict__ W2, const float* __restrict__ b2,
                                             float* __restrict__ out) {
    int g = blockIdx.x;
    int c = threadIdx.x;
    __shared__ float hc[H_ * L_ + GD_];
    __shared__ float zz[H_];
    int cn = gstart[g + 1] - gstart[g]; if (cn < 1) cn = 1;
    float ic = 1.f / (float)cn;
    for (int k = c; k < H_ * L_; k += 128)
        hc[k] = pooled[(k >> 7) * G_ * H_ + g * H_ + (k & 127)] * ic;
    if (c < GD_) hc[H_ * L_ + c] = gfeat[g * GD_ + c];
    __syncthreads();
    float z = b1[c];
#pragma unroll 4
    for (int k = 0; k < H_ * L_ + GD_; k++)
        z += hc[k] * W1[k * H_ + c];
    z = fmaxf(z, 0.f);
    zz[c] = z * W2[c];
    __syncthreads();
    for (int off = 64; off > 0; off >>= 1) {
        if (c < off) zz[c] += zz[c + off];
        __syncthreads();
    }
    if (c == 0) out[g] = zz[0] + b2[0];
}

// ---------------- launch ----------------

extern "C" void kernel_launch(void* const* d_in, const int* in_sizes, int n_in,
                              void* d_out, int out_size, void* d_ws, size_t ws_size,
                              hipStream_t stream) {
    const float* x0    = (const float*)d_in[0];
    const float* gfeat = (const float*)d_in[1];
    const float* Wsrc  = (const float*)d_in[2];
    const float* Wdst  = (const float*)d_in[3];
    const float* att   = (const float*)d_in[4];
    const float* bconv = (const float*)d_in[5];
    const float* gnw   = (const float*)d_in[6];
    const float* gnb   = (const float*)d_in[7];
    const float* gnms  = (const float*)d_in[8];
    const float* W1    = (const float*)d_in[9];
    const float* b1    = (const float*)d_in[10];
    const float* W2    = (const float*)d_in[11];
    const float* b2    = (const float*)d_in[12];
    const int*   eidx  = (const int*)d_in[13];
    const int*   batch = (const int*)d_in[14];
    const int* esrc = eidx;
    const int* edst = eidx + E_;
    float* out = (float*)d_out;

    char* w = (char*)d_ws;
    size_t off = 0;
    auto alloc = [&](size_t bytes) { char* p = w + off; off += (bytes + 255) & ~(size_t)255; return p; };
    ushort_t* xb    = (ushort_t*)alloc((size_t)N_ * H_ * 2);   // GEMM input (bf16), rewritten per layer
    ushort_t* xlb   = (ushort_t*)alloc((size_t)N_ * H_ * 2);
    float* xr     = (float*)alloc((size_t)N_ * H_ * 4);
    float* hbuf   = (float*)alloc((size_t)N_ * H_ * 4);
    ushort_t* Wt    = (ushort_t*)alloc((size_t)L_ * 256 * H_ * 2);
    int*   rowptr = (int*)alloc((size_t)(N_ + 1) * 4);
    int*   cursor = (int*)alloc((size_t)N_ * 4);
    int*   colarr = (int*)alloc((size_t)ETOT_ * 4);
    int*   bsum   = (int*)alloc(NSCAN * 4);
    int*   gstart = (int*)alloc((G_ + 1) * 4);
    float* gsum   = (float*)alloc(G_ * H_ * 4);
    float* gsq    = (float*)alloc(G_ * H_ * 4);
    float* pooled = (float*)alloc((size_t)L_ * G_ * H_ * 4);
    (void)ws_size; (void)in_sizes; (void)n_in; (void)out_size;

    // CSR build (dst-indexed, includes self-loops)
    k_init<<<(N_ + 255) / 256, 256, 0, stream>>>(cursor, pooled, gstart, batch);
    k_hist<<<(E_ + 255) / 256, 256, 0, stream>>>(edst, cursor);
    k_scan1<<<NSCAN, 256, 0, stream>>>(cursor, rowptr, bsum);
    k_scan2<<<1, 64, 0, stream>>>(bsum);
    k_scan3<<<(N_ + 255) / 256, 256, 0, stream>>>(rowptr, cursor, bsum);
    k_scatter<<<(E_ + N_ + 255) / 256, 256, 0, stream>>>(esrc, edst, cursor, colarr);

    // bf16 prep
    k_cvt<<<(N_ * H_ / 4 + 255) / 256, 256, 0, stream>>>(x0, xb);
    k_prep_w<<<(L_ * 256 * H_ + 255) / 256, 256, 0, stream>>>(Wsrc, Wdst, Wt);

    for (int l = 0; l < L_; l++) {
        k_mfma<<<(N_ / 16 + 3) / 4, 256, 0, stream>>>(xb, Wt + (size_t)l * 256 * H_, xlb, xr);
        k_conv<<<N_ / 16, 256, 0, stream>>>(xlb, xr, rowptr, colarr,
                                            att + (size_t)l * H_, bconv + (size_t)l * H_, hbuf);
        k_zero_gn<<<(G_ * H_ + 255) / 256, 256, 0, stream>>>(gsum, gsq);
        k_gn_stat<<<(N_ + 63) / 64, 256, 0, stream>>>(hbuf, batch, gsum, gsq);
        k_gn_fin<<<(G_ * H_ + 255) / 256, 256, 0, stream>>>(gsum, gsq, gstart,
                                                            gnw + (size_t)l * H_, gnms + (size_t)l * H_);
        k_gn_apply<<<(N_ + 63) / 64, 256, 0, stream>>>(hbuf, batch, gsum, gsq,
                                                       gnb + (size_t)l * H_, xb,
                                                       pooled + (size_t)l * G_ * H_);
    }

    k_mlp<<<G_, 128, 0, stream>>>(pooled, gfeat, gstart, W1, b1, W2, b2, out);
}

// Round 4
// 645.067 us; speedup vs baseline: 2.0644x; 1.2356x over previous
//
#include <hip/hip_runtime.h>
#include <hip/hip_bf16.h>
#include <math.h>

#define N_    100000
#define E_    1600000
#define ETOT_ 1700000   // E + N self-loops
#define G_    64
#define H_    128
#define L_    3
#define GD_   32
#define NEG_  0.2f
#define EPS_  1e-5f

#define NBUK_ 391       // ceil(N_/256) buckets of 256 dst nodes
#define CH_   8192      // edges per chunk
#define MCH_  196       // ceil(E_/CH_)

typedef unsigned short ushort_t;
typedef unsigned int uint_t;
typedef __attribute__((ext_vector_type(4))) float f32x4;
typedef __attribute__((ext_vector_type(8))) short bf16x8;
typedef __attribute__((ext_vector_type(8))) unsigned short ushort8;

__device__ __forceinline__ ushort_t bfb(float f) {
    __hip_bfloat16 h = __float2bfloat16(f);
    return *reinterpret_cast<ushort_t*>(&h);
}

// ---------------- misc init ----------------

__global__ void k_init(float* pooled, int* gstart, const int* __restrict__ batch) {
    int i = blockIdx.x * 256 + threadIdx.x;
    if (i < L_ * G_ * H_) pooled[i] = 0.f;
    if (i <= G_) {
        int lo = 0, hi = N_;
        while (lo < hi) { int mid = (lo + hi) >> 1; if (batch[mid] < i) lo = mid + 1; else hi = mid; }
        gstart[i] = lo;
    }
}

// ---------------- bucketed CSR build (no global atomics) ----------------

// counts C[bucket][chunk]
__global__ __launch_bounds__(256) void k_bcount(const int* __restrict__ edst, int* __restrict__ C) {
    __shared__ int hist[NBUK_];
    int t = threadIdx.x, m = blockIdx.x;
    for (int i = t; i < NBUK_; i += 256) hist[i] = 0;
    __syncthreads();
    int base = m * CH_;
#pragma unroll
    for (int j = 0; j < CH_ / 256; j++) {
        int e = base + j * 256 + t;
        if (e < E_) atomicAdd(&hist[edst[e] >> 8], 1);
    }
    __syncthreads();
    for (int i = t; i < NBUK_; i += 256) C[i * MCH_ + m] = hist[i];
}

// per-bucket exclusive scan over chunks; bucketEdges[b] = total
__global__ __launch_bounds__(256) void k_bscan(int* __restrict__ C, int* __restrict__ bucketEdges) {
    __shared__ int arr[256];
    int b = blockIdx.x, t = threadIdx.x;
    int v = (t < MCH_) ? C[b * MCH_ + t] : 0;
    arr[t] = v;
    __syncthreads();
    for (int off = 1; off < 256; off <<= 1) {
        int x = (t >= off) ? arr[t - off] : 0;
        __syncthreads();
        arr[t] += x;
        __syncthreads();
    }
    if (t < MCH_) C[b * MCH_ + t] = arr[t] - v;
    if (t == 255) bucketEdges[b] = arr[255];
}

// scan over buckets: bstartE (edges only), bstartT (edges + self-loops)
__global__ __launch_bounds__(512) void k_bscan2(const int* __restrict__ bucketEdges,
                                                int* __restrict__ bstartE, int* __restrict__ bstartT,
                                                int* __restrict__ rowptr) {
    __shared__ int aE[512], aT[512];
    int t = threadIdx.x;
    int e = 0, tot = 0;
    if (t < NBUK_) {
        e = bucketEdges[t];
        int nib = N_ - t * 256; if (nib > 256) nib = 256;
        tot = e + nib;
    }
    aE[t] = e; aT[t] = tot;
    __syncthreads();
    for (int off = 1; off < 512; off <<= 1) {
        int xe = (t >= off) ? aE[t - off] : 0;
        int xt = (t >= off) ? aT[t - off] : 0;
        __syncthreads();
        aE[t] += xe; aT[t] += xt;
        __syncthreads();
    }
    if (t < NBUK_) { bstartE[t] = aE[t] - e; bstartT[t] = aT[t] - tot; }
    if (t == 0) rowptr[N_] = ETOT_;
}

// stage (src,dst) pairs bucket-contiguously
__global__ __launch_bounds__(256) void k_bscatter(const int* __restrict__ esrc, const int* __restrict__ edst,
                                                  const int* __restrict__ C, const int* __restrict__ bstartE,
                                                  int2* __restrict__ stag) {
    __shared__ int cur[NBUK_];
    int t = threadIdx.x, m = blockIdx.x;
    for (int i = t; i < NBUK_; i += 256) cur[i] = C[i * MCH_ + m] + bstartE[i];
    __syncthreads();
    int base = m * CH_;
#pragma unroll
    for (int j = 0; j < CH_ / 256; j++) {
        int e = base + j * 256 + t;
        if (e < E_) {
            int s = esrc[e], d = edst[e];
            int pos = atomicAdd(&cur[d >> 8], 1);
            int2 p; p.x = s; p.y = d;
            stag[pos] = p;
        }
    }
}

// per-bucket: degree hist (+self-loop), scan -> rowptr, scatter -> colarr (L2-local window)
__global__ __launch_bounds__(256) void k_bfinal(const int2* __restrict__ stag,
                                                const int* __restrict__ bucketEdges,
                                                const int* __restrict__ bstartE, const int* __restrict__ bstartT,
                                                int* __restrict__ rowptr, int* __restrict__ colarr) {
    __shared__ int deg[256];
    __shared__ int cursor[256];
    int b = blockIdx.x, t = threadIdx.x;
    int nb0 = b * 256;
    int nib = N_ - nb0; if (nib > 256) nib = 256;
    int ebeg = bstartE[b], ecnt = bucketEdges[b];
    deg[t] = (t < nib) ? 1 : 0;
    __syncthreads();
    for (int i = t; i < ecnt; i += 256) {
        int2 p = stag[ebeg + i];
        atomicAdd(&deg[p.y - nb0], 1);
    }
    __syncthreads();
    int v = deg[t];
    cursor[t] = v;
    __syncthreads();
    for (int off = 1; off < 256; off <<= 1) {
        int x = (t >= off) ? cursor[t - off] : 0;
        __syncthreads();
        cursor[t] += x;
        __syncthreads();
    }
    int excl = cursor[t] - v;
    int rowbase = bstartT[b];
    if (t < nib) {
        rowptr[nb0 + t] = rowbase + excl;
        colarr[rowbase + excl] = nb0 + t;   // self-loop first
    }
    __syncthreads();
    cursor[t] = excl + 1;
    __syncthreads();
    for (int i = t; i < ecnt; i += 256) {
        int2 p = stag[ebeg + i];
        int pos = atomicAdd(&cursor[p.y - nb0], 1);
        colarr[rowbase + pos] = p.x;
    }
}

// ---------------- bf16 conversions ----------------

__global__ void k_cvt(const float* __restrict__ x, ushort_t* __restrict__ xb) {
    int i = blockIdx.x * 256 + threadIdx.x;   // one float4 per thread
    float4 v = *(const float4*)(x + (size_t)i * 4);
    ushort4 o;
    o.x = bfb(v.x); o.y = bfb(v.y); o.z = bfb(v.z); o.w = bfb(v.w);
    *(ushort4*)(xb + (size_t)i * 4) = o;
}

// Wt[l][c][k] = bf16( c<128 ? Ws[l][k][c] : Wd[l][k][c-128] )
__global__ void k_prep_w(const float* __restrict__ Ws, const float* __restrict__ Wd,
                         ushort_t* __restrict__ Wt) {
    int i = blockIdx.x * 256 + threadIdx.x;
    if (i >= L_ * 256 * H_) return;
    int l = i >> 15;
    int r = i & 32767;
    int c = r >> 7, k = r & 127;
    float v = (c < H_) ? Ws[(size_t)l * H_ * H_ + k * H_ + c]
                       : Wd[(size_t)l * H_ * H_ + k * H_ + (c - H_)];
    Wt[i] = bfb(v);
}

// ---------------- MFMA GEMM: [N,128]bf16 @ [128,256]bf16 -> xlb bf16, xr f32 ----------------

__global__ __launch_bounds__(256) void k_mfma(const ushort_t* __restrict__ xb,
                                              const ushort_t* __restrict__ Wt,
                                              ushort_t* __restrict__ xlb,
                                              float* __restrict__ xr) {
    int wv = threadIdx.x >> 6, lane = threadIdx.x & 63;
    int wt = blockIdx.x * 4 + wv;
    int row0 = wt * 16;
    if (row0 >= N_) return;
    int sl = lane & 15, q = lane >> 4;

    bf16x8 a[4];
    const ushort_t* ap = xb + (size_t)(row0 + sl) * H_ + q * 8;
#pragma unroll
    for (int kk = 0; kk < 4; kk++) a[kk] = *(const bf16x8*)(ap + kk * 32);

    f32x4 acc[16];
#pragma unroll
    for (int c = 0; c < 16; c++) acc[c] = (f32x4){0.f, 0.f, 0.f, 0.f};

#pragma unroll
    for (int c = 0; c < 16; c++) {
        const ushort_t* bp = Wt + (size_t)(c * 16 + sl) * H_ + q * 8;
#pragma unroll
        for (int kk = 0; kk < 4; kk++) {
            bf16x8 b = *(const bf16x8*)(bp + kk * 32);
            acc[c] = __builtin_amdgcn_mfma_f32_16x16x32_bf16(a[kk], b, acc[c], 0, 0, 0);
        }
    }

    int orow = row0 + q * 4;
#pragma unroll
    for (int c = 0; c < 8; c++)
#pragma unroll
        for (int j = 0; j < 4; j++)
            xlb[(size_t)(orow + j) * H_ + c * 16 + sl] = bfb(acc[c][j]);
#pragma unroll
    for (int c = 8; c < 16; c++)
#pragma unroll
        for (int j = 0; j < 4; j++)
            xr[(size_t)(orow + j) * H_ + (c - 8) * 16 + sl] = acc[c][j];
}

// ---------------- GATv2 conv: 16 lanes x 8 dims per dst row, no-max softmax ----------------

__global__ __launch_bounds__(256) void k_conv(const ushort_t* __restrict__ xlb, const float* __restrict__ xr,
                                              const int* __restrict__ rowptr, const int* __restrict__ colarr,
                                              const float* __restrict__ attl, const float* __restrict__ bcl,
                                              float* __restrict__ h) {
    int tid = threadIdx.x;
    int lane = tid & 63, wv = tid >> 6;
    int sl = lane & 15, q = lane >> 4;
    int row = blockIdx.x * 16 + wv * 4 + q;
    int d0 = sl * 8;

    float xrv[8], av[8], av5[8];
    {
        float4 t0 = *(const float4*)(xr + (size_t)row * H_ + d0);
        float4 t1 = *(const float4*)(xr + (size_t)row * H_ + d0 + 4);
        xrv[0] = t0.x; xrv[1] = t0.y; xrv[2] = t0.z; xrv[3] = t0.w;
        xrv[4] = t1.x; xrv[5] = t1.y; xrv[6] = t1.z; xrv[7] = t1.w;
        float4 a0 = *(const float4*)(attl + d0);
        float4 a1 = *(const float4*)(attl + d0 + 4);
        av[0] = a0.x; av[1] = a0.y; av[2] = a0.z; av[3] = a0.w;
        av[4] = a1.x; av[5] = a1.y; av[6] = a1.z; av[7] = a1.w;
#pragma unroll
        for (int e = 0; e < 8; e++) av5[e] = NEG_ * av[e];
    }

    int jb = rowptr[row];
    int n = rowptr[row + 1] - jb;

    float ssum = 0.f;
    float ac[8] = {0.f, 0.f, 0.f, 0.f, 0.f, 0.f, 0.f, 0.f};

    int s = (n > 0) ? colarr[jb] : 0;
    for (int i = 0; i < n; i++) {
        int snext = (i + 1 < n) ? colarr[jb + i + 1] : 0;
        ushort8 u = *(const ushort8*)(xlb + (size_t)s * H_ + d0);
        float v[8];
        float p = 0.f;
#pragma unroll
        for (int e = 0; e < 8; e++) {
            v[e] = __uint_as_float(((uint_t)u[e]) << 16);
            float t = v[e] + xrv[e];
            p = fmaf(t, (t > 0.f ? av[e] : av5[e]), p);
        }
        p += __shfl_xor(p, 8);
        p += __shfl_xor(p, 4);
        p += __shfl_xor(p, 2);
        p += __shfl_xor(p, 1);
        float wgt = __expf(p);
        ssum += wgt;
#pragma unroll
        for (int e = 0; e < 8; e++) ac[e] = fmaf(wgt, v[e], ac[e]);
        s = snext;
    }

    float inv = 1.f / ssum;
    float4 b0 = *(const float4*)(bcl + d0);
    float4 b1 = *(const float4*)(bcl + d0 + 4);
    float4 o0 = { ac[0] * inv + b0.x, ac[1] * inv + b0.y, ac[2] * inv + b0.z, ac[3] * inv + b0.w };
    float4 o1 = { ac[4] * inv + b1.x, ac[5] * inv + b1.y, ac[6] * inv + b1.z, ac[7] * inv + b1.w };
    *(float4*)(h + (size_t)row * H_ + d0) = o0;
    *(float4*)(h + (size_t)row * H_ + d0 + 4) = o1;
}

// ---------------- GraphNorm (+ReLU, +pool) ----------------

__global__ void k_zero_gn(float* gsum, float* gsq) {
    int i = blockIdx.x * 256 + threadIdx.x;
    if (i < G_ * H_) { gsum[i] = 0.f; gsq[i] = 0.f; }
}

__global__ void k_gn_stat(const float* __restrict__ h, const int* __restrict__ batch,
                          float* gsum, float* gsq) {
    int tid = threadIdx.x;
    int nb = blockIdx.x * 64;
    int d = tid & 127, hh = tid >> 7;
    int nend = nb + 64; if (nend > N_) nend = N_;
    float s1 = 0.f, s2 = 0.f; int curg = -1;
    for (int n = nb + hh; n < nend; n += 2) {
        int g = batch[n];
        if (g != curg) {
            if (curg >= 0) { atomicAdd(&gsum[curg * H_ + d], s1); atomicAdd(&gsq[curg * H_ + d], s2); }
            s1 = 0.f; s2 = 0.f; curg = g;
        }
        float v = h[(size_t)n * H_ + d];
        s1 += v; s2 += v * v;
    }
    if (curg >= 0) { atomicAdd(&gsum[curg * H_ + d], s1); atomicAdd(&gsq[curg * H_ + d], s2); }
}

// gsum -> mv = ms*mean ; gsq -> iv = gn_w * rsqrt(var + eps)
__global__ void k_gn_fin(float* gsum, float* gsq, const int* __restrict__ gstart,
                         const float* __restrict__ gnwl, const float* __restrict__ gnmsl) {
    int i = blockIdx.x * 256 + threadIdx.x;
    if (i < G_ * H_) {
        int g = i >> 7, d = i & 127;
        int c = gstart[g + 1] - gstart[g]; if (c < 1) c = 1;
        float ic = 1.f / (float)c;
        float mean = gsum[i] * ic;
        float e2   = gsq[i] * ic;
        float ms = gnmsl[d];
        float var = e2 - ms * (2.f - ms) * mean * mean;
        gsum[i] = ms * mean;
        gsq[i]  = gnwl[d] * rsqrtf(var + EPS_);
    }
}

// apply + relu + pool; writes next-layer GEMM input as bf16
__global__ void k_gn_apply(const float* __restrict__ h, const int* __restrict__ batch,
                           const float* __restrict__ gmv, const float* __restrict__ giv,
                           const float* __restrict__ gnbl,
                           ushort_t* __restrict__ hb, float* pooled_l) {
    int tid = threadIdx.x;
    int nb = blockIdx.x * 64;
    int d = tid & 127, hh = tid >> 7;
    int nend = nb + 64; if (nend > N_) nend = N_;
    float bb = gnbl[d];
    float pacc = 0.f; int curg = -1; float mv = 0.f, iv = 0.f;
    for (int n = nb + hh; n < nend; n += 2) {
        int g = batch[n];
        if (g != curg) {
            if (curg >= 0) atomicAdd(&pooled_l[curg * H_ + d], pacc);
            pacc = 0.f; curg = g;
            mv = gmv[g * H_ + d];
            iv = giv[g * H_ + d];
        }
        float v = (h[(size_t)n * H_ + d] - mv) * iv + bb;
        v = fmaxf(v, 0.f);
        hb[(size_t)n * H_ + d] = bfb(v);
        pacc += v;
    }
    if (curg >= 0) atomicAdd(&pooled_l[curg * H_ + d], pacc);
}

// ---------------- final MLP ----------------

__global__ __launch_bounds__(128) void k_mlp(const float* __restrict__ pooled, const float* __restrict__ gfeat,
                                             const int* __restrict__ gstart,
                                             const float* __restrict__ W1, const float* __restrict__ b1,
                                             const float* __restrict__ W2, const float* __restrict__ b2,
                                             float* __restrict__ out) {
    int g = blockIdx.x;
    int c = threadIdx.x;
    __shared__ float hc[H_ * L_ + GD_];
    __shared__ float zz[H_];
    int cn = gstart[g + 1] - gstart[g]; if (cn < 1) cn = 1;
    float ic = 1.f / (float)cn;
    for (int k = c; k < H_ * L_; k += 128)
        hc[k] = pooled[(k >> 7) * G_ * H_ + g * H_ + (k & 127)] * ic;
    if (c < GD_) hc[H_ * L_ + c] = gfeat[g * GD_ + c];
    __syncthreads();
    float z = b1[c];
#pragma unroll 4
    for (int k = 0; k < H_ * L_ + GD_; k++)
        z += hc[k] * W1[k * H_ + c];
    z = fmaxf(z, 0.f);
    zz[c] = z * W2[c];
    __syncthreads();
    for (int off = 64; off > 0; off >>= 1) {
        if (c < off) zz[c] += zz[c + off];
        __syncthreads();
    }
    if (c == 0) out[g] = zz[0] + b2[0];
}

// ---------------- launch ----------------

extern "C" void kernel_launch(void* const* d_in, const int* in_sizes, int n_in,
                              void* d_out, int out_size, void* d_ws, size_t ws_size,
                              hipStream_t stream) {
    const float* x0    = (const float*)d_in[0];
    const float* gfeat = (const float*)d_in[1];
    const float* Wsrc  = (const float*)d_in[2];
    const float* Wdst  = (const float*)d_in[3];
    const float* att   = (const float*)d_in[4];
    const float* bconv = (const float*)d_in[5];
    const float* gnw   = (const float*)d_in[6];
    const float* gnb   = (const float*)d_in[7];
    const float* gnms  = (const float*)d_in[8];
    const float* W1    = (const float*)d_in[9];
    const float* b1    = (const float*)d_in[10];
    const float* W2    = (const float*)d_in[11];
    const float* b2    = (const float*)d_in[12];
    const int*   eidx  = (const int*)d_in[13];
    const int*   batch = (const int*)d_in[14];
    const int* esrc = eidx;
    const int* edst = eidx + E_;
    float* out = (float*)d_out;

    char* w = (char*)d_ws;
    size_t off = 0;
    auto alloc = [&](size_t bytes) { char* p = w + off; off += (bytes + 255) & ~(size_t)255; return p; };
    ushort_t* xb    = (ushort_t*)alloc((size_t)N_ * H_ * 2);   // GEMM input (bf16), rewritten per layer
    ushort_t* xlb   = (ushort_t*)alloc((size_t)N_ * H_ * 2);
    float* xr     = (float*)alloc((size_t)N_ * H_ * 4);
    float* hbuf   = (float*)alloc((size_t)N_ * H_ * 4);
    ushort_t* Wt    = (ushort_t*)alloc((size_t)L_ * 256 * H_ * 2);
    int*   rowptr = (int*)alloc((size_t)(N_ + 1) * 4);
    int*   colarr = (int*)alloc((size_t)ETOT_ * 4);
    int*   bktE   = (int*)alloc(NBUK_ * 4);
    int*   bstartE= (int*)alloc(NBUK_ * 4);
    int*   bstartT= (int*)alloc(NBUK_ * 4);
    int*   gstart = (int*)alloc((G_ + 1) * 4);
    float* gsum   = (float*)alloc(G_ * H_ * 4);
    float* gsq    = (float*)alloc(G_ * H_ * 4);
    float* pooled = (float*)alloc((size_t)L_ * G_ * H_ * 4);
    // aliases: used only BEFORE xr/hbuf are first written (same-stream ordering)
    int2* stag = (int2*)xr;             // E_*8B = 12.8MB <= 51.2MB
    int*  C    = (int*)hbuf;            // NBUK_*MCH_*4B = 306KB <= 51.2MB
    (void)ws_size; (void)in_sizes; (void)n_in; (void)out_size;

    // bucketed CSR build (dst-indexed, self-loop first per row)
    k_init<<<(N_ + 255) / 256, 256, 0, stream>>>(pooled, gstart, batch);
    k_bcount<<<MCH_, 256, 0, stream>>>(edst, C);
    k_bscan<<<NBUK_, 256, 0, stream>>>(C, bktE);
    k_bscan2<<<1, 512, 0, stream>>>(bktE, bstartE, bstartT, rowptr);
    k_bscatter<<<MCH_, 256, 0, stream>>>(esrc, edst, C, bstartE, stag);
    k_bfinal<<<NBUK_, 256, 0, stream>>>(stag, bktE, bstartE, bstartT, rowptr, colarr);

    // bf16 prep
    k_cvt<<<(N_ * H_ / 4 + 255) / 256, 256, 0, stream>>>(x0, xb);
    k_prep_w<<<(L_ * 256 * H_ + 255) / 256, 256, 0, stream>>>(Wsrc, Wdst, Wt);

    for (int l = 0; l < L_; l++) {
        k_mfma<<<(N_ / 16 + 3) / 4, 256, 0, stream>>>(xb, Wt + (size_t)l * 256 * H_, xlb, xr);
        k_conv<<<N_ / 16, 256, 0, stream>>>(xlb, xr, rowptr, colarr,
                                            att + (size_t)l * H_, bconv + (size_t)l * H_, hbuf);
        k_zero_gn<<<(G_ * H_ + 255) / 256, 256, 0, stream>>>(gsum, gsq);
        k_gn_stat<<<(N_ + 63) / 64, 256, 0, stream>>>(hbuf, batch, gsum, gsq);
        k_gn_fin<<<(G_ * H_ + 255) / 256, 256, 0, stream>>>(gsum, gsq, gstart,
                                                            gnw + (size_t)l * H_, gnms + (size_t)l * H_);
        k_gn_apply<<<(N_ + 63) / 64, 256, 0, stream>>>(hbuf, batch, gsum, gsq,
                                                       gnb + (size_t)l * H_, xb,
                                                       pooled + (size_t)l * G_ * H_);
    }

    k_mlp<<<G_, 128, 0, stream>>>(pooled, gfeat, gstart, W1, b1, W2, b2, out);
}